// Round 1
// baseline (988.562 us; speedup 1.0000x reference)
//
#include <hip/hip_runtime.h>

// Problem constants
constexpr int Bn = 8192;   // batch
constexpr int Dd = 2048;   // dims
constexpr int Kk = 512;    // components
constexpr int Qq = 8;      // factors
constexpr int Nn = Kk * 9; // GEMM N: 8 PinvW cols + 1 g col per component = 4608
constexpr float DLOG2PI = 3763.9722f; // D * log(2*pi)

// GEMM tiling
constexpr int BM = 128, BN = 144, BK = 32;

// Workspace layout (bytes)
constexpr size_t OFF_PSI   = 0;          // psi_inv: D*4
constexpr size_t OFF_LDP   = 8192;       // logdetPsi scalar
constexpr size_t OFF_LOGPI = 8448;       // K*4
constexpr size_t OFF_OFFK  = 10752;      // K*4
constexpr size_t OFF_MINV  = 13056;      // K*64*4
constexpr size_t OFF_XPX   = 144384;     // B*4
constexpr size_t OFF_XBF   = 177408;     // B*D*2
constexpr size_t OFF_GT    = 33731840;   // N*D*2  (Gt[n][d], k-contig rows)
constexpr size_t OFF_LL    = 52606208;   // B*K*4
constexpr size_t OFF_PART  = 69383424;   // 2048*4

typedef __bf16 bf16x8 __attribute__((ext_vector_type(8)));
typedef float f32x4 __attribute__((ext_vector_type(4)));

__device__ inline float softplusf(float x) {
  return fmaxf(x, 0.f) + log1pf(expf(-fabsf(x)));
}
__device__ inline unsigned short f2bf(float x) {
  unsigned int u = __builtin_bit_cast(unsigned int, x);
  u = (u + 0x7fffu + ((u >> 16) & 1u)) >> 16;
  return (unsigned short)u;
}
__device__ inline unsigned int pack2(float a, float b) {
  return (unsigned int)f2bf(a) | ((unsigned int)f2bf(b) << 16);
}

// ---------------- Kernel A: psi, logdetPsi, log_pi ----------------
__global__ __launch_bounds__(256) void prep_psi(
    const float* __restrict__ psi_rho, const float* __restrict__ pi_logits,
    float* __restrict__ psi_inv, float* __restrict__ logdetPsi,
    float* __restrict__ logpi) {
  __shared__ float red[256];
  int t = threadIdx.x;
  float acc = 0.f;
  for (int d = t; d < Dd; d += 256) {
    float p = softplusf(psi_rho[d]) + 1e-5f;
    psi_inv[d] = 1.f / p;
    acc += logf(p);
  }
  red[t] = acc;
  __syncthreads();
  for (int s = 128; s > 0; s >>= 1) { if (t < s) red[t] += red[t + s]; __syncthreads(); }
  if (t == 0) *logdetPsi = red[0];
  __syncthreads();
  float mx = -3.4e38f;
  for (int i = t; i < Kk; i += 256) mx = fmaxf(mx, pi_logits[i]);
  red[t] = mx;
  __syncthreads();
  for (int s = 128; s > 0; s >>= 1) { if (t < s) red[t] = fmaxf(red[t], red[t + s]); __syncthreads(); }
  mx = red[0];
  __syncthreads();
  float se = 0.f;
  for (int i = t; i < Kk; i += 256) se += expf(pi_logits[i] - mx);
  red[t] = se;
  __syncthreads();
  for (int s = 128; s > 0; s >>= 1) { if (t < s) red[t] += red[t + s]; __syncthreads(); }
  float lse = mx + logf(red[0]);
  for (int i = t; i < Kk; i += 256) logpi[i] = pi_logits[i] - lse;
}

// ---------------- Kernel B: per-component precompute + G columns ----------------
__global__ __launch_bounds__(256) void prep_k(
    const float* __restrict__ mu, const float* __restrict__ dir_raw,
    const float* __restrict__ scale_rho, const float* __restrict__ psi_inv,
    const float* __restrict__ logdetPsi, const float* __restrict__ logpi,
    float* __restrict__ offk, float* __restrict__ Minv,
    unsigned short* __restrict__ Gt) {
  int k = blockIdx.x, t = threadIdx.x, lane = t & 63, w = t >> 6;
  float vals[53];
#pragma unroll
  for (int i = 0; i < 53; i++) vals[i] = 0.f;
  const float4* dirp = (const float4*)(dir_raw + (size_t)k * Dd * Qq);
  for (int d = t; d < Dd; d += 256) {
    float4 da = dirp[d * 2], db = dirp[d * 2 + 1];
    float dir8[8] = {da.x, da.y, da.z, da.w, db.x, db.y, db.z, db.w};
    float pw = psi_inv[d];
    float md = mu[(size_t)k * Dd + d];
    int c = 0;
#pragma unroll
    for (int i = 0; i < 8; i++) {
      float dip = dir8[i] * pw;
#pragma unroll
      for (int j = i; j < 8; j++) { vals[c] += dip * dir8[j]; c++; }
    }
#pragma unroll
    for (int q = 0; q < 8; q++) vals[36 + q] += dir8[q] * dir8[q];
    float mp = md * pw;
#pragma unroll
    for (int q = 0; q < 8; q++) vals[44 + q] += mp * dir8[q];
    vals[52] += md * mp;
  }
  __shared__ float redk[4 * 53];
#pragma unroll
  for (int v = 0; v < 53; v++) {
    float val = vals[v];
#pragma unroll
    for (int o = 32; o; o >>= 1) val += __shfl_down(val, o, 64);
    if (lane == 0) redk[w * 53 + v] = val;
  }
  __syncthreads();
  __shared__ float R[53];
  __shared__ float sAl[8], sHh[8];
  if (t < 53) R[t] = redk[t] + redk[53 + t] + redk[106 + t] + redk[159 + t];
  __syncthreads();
  if (t == 0) {
    float Sf[8][8];
    {
      int c2 = 0;
      for (int i = 0; i < 8; i++)
        for (int j = i; j < 8; j++) { float v = R[c2++]; Sf[i][j] = v; Sf[j][i] = v; }
    }
    float alpha[8];
    for (int q = 0; q < 8; q++) {
      float nr = fmaxf(sqrtf(R[36 + q]), 1e-5f);
      alpha[q] = softplusf(scale_rho[(size_t)k * 8 + q]) / nr;
    }
    float Mm[8][8];
    for (int i = 0; i < 8; i++)
      for (int j = 0; j < 8; j++)
        Mm[i][j] = alpha[i] * alpha[j] * Sf[i][j] + (i == j ? 1.f : 0.f);
    float L[8][8] = {};
    for (int i = 0; i < 8; i++) {
      for (int j = 0; j <= i; j++) {
        float s2 = Mm[i][j];
        for (int p = 0; p < j; p++) s2 -= L[i][p] * L[j][p];
        if (i == j) L[i][i] = sqrtf(s2);
        else        L[i][j] = s2 / L[j][j];
      }
    }
    float logdetM = 0.f;
    for (int i = 0; i < 8; i++) logdetM += 2.f * logf(L[i][i]);
    float wv[8];
    for (int q = 0; q < 8; q++) wv[q] = alpha[q] * R[44 + q];
    float y[8], h[8];
    for (int i = 0; i < 8; i++) {
      float s2 = wv[i];
      for (int p = 0; p < i; p++) s2 -= L[i][p] * y[p];
      y[i] = s2 / L[i][i];
    }
    for (int i = 7; i >= 0; i--) {
      float s2 = y[i];
      for (int p = i + 1; p < 8; p++) s2 -= L[p][i] * h[p];
      h[i] = s2 / L[i][i];
    }
    float cc = R[52];
    for (int q = 0; q < 8; q++) cc -= wv[q] * h[q];
    for (int col = 0; col < 8; col++) {
      float yy[8], z[8];
      for (int i = 0; i < 8; i++) {
        float s2 = (i == col) ? 1.f : 0.f;
        for (int p = 0; p < i; p++) s2 -= L[i][p] * yy[p];
        yy[i] = s2 / L[i][i];
      }
      for (int i = 7; i >= 0; i--) {
        float s2 = yy[i];
        for (int p = i + 1; p < 8; p++) s2 -= L[p][i] * z[p];
        z[i] = s2 / L[i][i];
      }
      for (int r2 = 0; r2 < 8; r2++) Minv[(size_t)k * 64 + r2 * 8 + col] = z[r2];
    }
    offk[k] = -0.5f * (DLOG2PI + logdetPsi[0] + logdetM + cc) + logpi[k];
    for (int q = 0; q < 8; q++) { sAl[q] = alpha[q]; sHh[q] = h[q]; }
  }
  __syncthreads();
  float al[8], hh[8];
#pragma unroll
  for (int q = 0; q < 8; q++) { al[q] = sAl[q]; hh[q] = sHh[q]; }
  // Pass 2: write Gt rows (k*9+q): q<8 -> psi_inv*W col; q=8 -> g = psi_inv*(mu - W h)
  for (int d = t; d < Dd; d += 256) {
    float4 da = dirp[d * 2], db = dirp[d * 2 + 1];
    float dir8[8] = {da.x, da.y, da.z, da.w, db.x, db.y, db.z, db.w};
    float pw = psi_inv[d];
    float md = mu[(size_t)k * Dd + d];
    float gs = 0.f;
#pragma unroll
    for (int q = 0; q < 8; q++) {
      Gt[((size_t)(k * 9 + q)) * Dd + d] = f2bf(pw * al[q] * dir8[q]);
      gs += al[q] * dir8[q] * hh[q];
    }
    Gt[((size_t)(k * 9 + 8)) * Dd + d] = f2bf(pw * (md - gs));
  }
}

// ---------------- Kernel C: x -> bf16, xT Psi^-1 x ----------------
__global__ __launch_bounds__(256) void prep_x(
    const float* __restrict__ x, const float* __restrict__ psi_inv,
    unsigned short* __restrict__ xbf, float* __restrict__ xPx) {
  int b = blockIdx.x, t = threadIdx.x, lane = t & 63, w = t >> 6;
  const float4* xr = (const float4*)(x + (size_t)b * Dd);
  const float4* pr = (const float4*)psi_inv;
  float4 v0 = xr[2 * t], v1 = xr[2 * t + 1];
  float4 p0 = pr[2 * t], p1 = pr[2 * t + 1];
  float acc = v0.x * v0.x * p0.x + v0.y * v0.y * p0.y + v0.z * v0.z * p0.z + v0.w * v0.w * p0.w
            + v1.x * v1.x * p1.x + v1.y * v1.y * p1.y + v1.z * v1.z * p1.z + v1.w * v1.w * p1.w;
  uint4 o;
  o.x = pack2(v0.x, v0.y); o.y = pack2(v0.z, v0.w);
  o.z = pack2(v1.x, v1.y); o.w = pack2(v1.z, v1.w);
  *(uint4*)(xbf + (size_t)b * Dd + t * 8) = o;
#pragma unroll
  for (int s2 = 32; s2; s2 >>= 1) acc += __shfl_down(acc, s2, 64);
  __shared__ float r4[4];
  if (lane == 0) r4[w] = acc;
  __syncthreads();
  if (t == 0) xPx[b] = r4[0] + r4[1] + r4[2] + r4[3];
}

// ---------------- Kernel D: fused GEMM + ll epilogue ----------------
__global__ __launch_bounds__(256) void gemm_ll(
    const unsigned short* __restrict__ xbf, const unsigned short* __restrict__ Gt,
    const float* __restrict__ Minv, const float* __restrict__ offk,
    const float* __restrict__ xPx, float* __restrict__ ll) {
  __shared__ char smem[36864 + 4096 + 64];
  unsigned short* As = (unsigned short*)smem;           // [128][32] bf16
  unsigned short* Bs = (unsigned short*)(smem + 8192);  // [144][32] bf16
  float* Cs    = (float*)smem;                          // [4][16][144] f32 (union w/ As/Bs)
  float* sMinv = (float*)(smem + 36864);                // [16][64]
  float* sOff  = (float*)(smem + 36864 + 4096);         // [16]

  int t = threadIdx.x, lane = t & 63, w = t >> 6;
  int m0 = blockIdx.y * BM;
  int n0 = blockIdx.x * BN;
  int comp0 = blockIdx.x * 16;

  for (int i = t; i < 1024; i += 256) sMinv[i] = Minv[(size_t)comp0 * 64 + i];
  if (t < 16) sOff[t] = offk[comp0 + t];

  f32x4 acc[2][9];
  f32x4 zero = {0.f, 0.f, 0.f, 0.f};
#pragma unroll
  for (int mt = 0; mt < 2; mt++)
#pragma unroll
    for (int nt = 0; nt < 9; nt++) acc[mt][nt] = zero;

  int kofs = (lane >> 4) * 8;
  int r16 = lane & 15;

  for (int k0 = 0; k0 < Dd; k0 += BK) {
    __syncthreads();
#pragma unroll
    for (int it = 0; it < 2; ++it) {
      int ch = it * 256 + t;
      int rr = ch >> 2, cc = ch & 3;
      *(uint4*)(As + rr * BK + cc * 8) =
          *(const uint4*)(xbf + (size_t)(m0 + rr) * Dd + k0 + cc * 8);
    }
#pragma unroll
    for (int it = 0; it < 3; ++it) {
      int ch = it * 256 + t;
      if (ch < 576) {
        int rr = ch >> 2, cc = ch & 3;
        *(uint4*)(Bs + rr * BK + cc * 8) =
            *(const uint4*)(Gt + (size_t)(n0 + rr) * Dd + k0 + cc * 8);
      }
    }
    __syncthreads();
    bf16x8 a0 = *(const bf16x8*)(As + (w * 32 + r16) * BK + kofs);
    bf16x8 a1 = *(const bf16x8*)(As + (w * 32 + 16 + r16) * BK + kofs);
#pragma unroll
    for (int nt = 0; nt < 9; ++nt) {
      bf16x8 bfr = *(const bf16x8*)(Bs + (nt * 16 + r16) * BK + kofs);
      acc[0][nt] = __builtin_amdgcn_mfma_f32_16x16x32_bf16(a0, bfr, acc[0][nt], 0, 0, 0);
      acc[1][nt] = __builtin_amdgcn_mfma_f32_16x16x32_bf16(a1, bfr, acc[1][nt], 0, 0, 0);
    }
  }

  // Epilogue: per wave, round-trip its 16x144 sub-tile through LDS, compute ll
  float* myC = Cs + w * (16 * 144);
#pragma unroll
  for (int mt = 0; mt < 2; ++mt) {
    __syncthreads();
#pragma unroll
    for (int nt = 0; nt < 9; ++nt) {
#pragma unroll
      for (int r = 0; r < 4; r++) {
        myC[((lane >> 4) * 4 + r) * 144 + nt * 16 + r16] = acc[mt][nt][r];
      }
    }
    __syncthreads();
#pragma unroll
    for (int i = 0; i < 4; i++) {
      int cell = lane + 64 * i;
      int row_l = cell >> 4, cl = cell & 15;
      int b = m0 + w * 32 + mt * 16 + row_l;
      const float* cp = myC + row_l * 144 + cl * 9;
      float u[8];
#pragma unroll
      for (int j = 0; j < 8; j++) u[j] = cp[j];
      float s = cp[8];
      const float* Mi = sMinv + cl * 64;
      float tq = 0.f;
#pragma unroll
      for (int a2 = 0; a2 < 8; a2++) {
#pragma unroll
        for (int b2 = 0; b2 < 8; b2++) tq += u[a2] * Mi[a2 * 8 + b2] * u[b2];
      }
      ll[(size_t)b * Kk + comp0 + cl] = sOff[cl] + s + 0.5f * tq - 0.5f * xPx[b];
    }
  }
}

// ---------------- Kernel E1: logsumexp per row -> block partials ----------------
__global__ __launch_bounds__(256) void lse_rows(
    const float* __restrict__ ll, float* __restrict__ part) {
  int t = threadIdx.x, lane = t & 63, w = t >> 6;
  int b = blockIdx.x * 4 + w;
  const float* row = ll + (size_t)b * Kk;
  float v[8];
  float mx = -3.4e38f;
#pragma unroll
  for (int i = 0; i < 8; i++) { v[i] = row[lane + 64 * i]; mx = fmaxf(mx, v[i]); }
#pragma unroll
  for (int o = 32; o; o >>= 1) mx = fmaxf(mx, __shfl_xor(mx, o, 64));
  float se = 0.f;
#pragma unroll
  for (int i = 0; i < 8; i++) se += expf(v[i] - mx);
#pragma unroll
  for (int o = 32; o; o >>= 1) se += __shfl_xor(se, o, 64);
  __shared__ float r4[4];
  if (lane == 0) r4[w] = -(mx + logf(se));
  __syncthreads();
  if (t == 0) part[blockIdx.x] = r4[0] + r4[1] + r4[2] + r4[3];
}

// ---------------- Kernel E2: final mean ----------------
__global__ __launch_bounds__(256) void final_mean(
    const float* __restrict__ part, float* __restrict__ out) {
  int t = threadIdx.x, lane = t & 63, w = t >> 6;
  float acc = 0.f;
  for (int i = t; i < 2048; i += 256) acc += part[i];
#pragma unroll
  for (int o = 32; o; o >>= 1) acc += __shfl_down(acc, o, 64);
  __shared__ float r4[4];
  if (lane == 0) r4[w] = acc;
  __syncthreads();
  if (t == 0) out[0] = (r4[0] + r4[1] + r4[2] + r4[3]) * (1.0f / 8192.0f);
}

extern "C" void kernel_launch(void* const* d_in, const int* in_sizes, int n_in,
                              void* d_out, int out_size, void* d_ws, size_t ws_size,
                              hipStream_t stream) {
  const float* x         = (const float*)d_in[0];
  const float* mu        = (const float*)d_in[1];
  const float* dir_raw   = (const float*)d_in[2];
  const float* scale_rho = (const float*)d_in[3];
  const float* psi_rho   = (const float*)d_in[4];
  const float* pi_logits = (const float*)d_in[5];
  float* out = (float*)d_out;
  char* ws = (char*)d_ws;

  float* psi_inv          = (float*)(ws + OFF_PSI);
  float* logdetPsi        = (float*)(ws + OFF_LDP);
  float* logpi            = (float*)(ws + OFF_LOGPI);
  float* offk             = (float*)(ws + OFF_OFFK);
  float* Minv             = (float*)(ws + OFF_MINV);
  float* xPx              = (float*)(ws + OFF_XPX);
  unsigned short* xbf     = (unsigned short*)(ws + OFF_XBF);
  unsigned short* Gt      = (unsigned short*)(ws + OFF_GT);
  float* ll               = (float*)(ws + OFF_LL);
  float* part             = (float*)(ws + OFF_PART);

  prep_psi<<<1, 256, 0, stream>>>(psi_rho, pi_logits, psi_inv, logdetPsi, logpi);
  prep_k<<<Kk, 256, 0, stream>>>(mu, dir_raw, scale_rho, psi_inv, logdetPsi, logpi,
                                 offk, Minv, Gt);
  prep_x<<<Bn, 256, 0, stream>>>(x, psi_inv, xbf, xPx);
  dim3 g(Nn / BN, Bn / BM);  // (32, 64)
  gemm_ll<<<g, 256, 0, stream>>>(xbf, Gt, Minv, offk, xPx, ll);
  lse_rows<<<Bn / 4, 256, 0, stream>>>(ll, part);
  final_mean<<<1, 256, 0, stream>>>(part, out);
}

// Round 2
// 543.354 us; speedup vs baseline: 1.8194x; 1.8194x over previous
//
#include <hip/hip_runtime.h>

// Problem constants
constexpr int Bn = 8192;   // batch
constexpr int Dd = 2048;   // dims
constexpr int Kk = 512;    // components
constexpr int Qq = 8;      // factors
constexpr int Nn = Kk * 9; // GEMM N: 8 PinvW cols + 1 g col per component = 4608
constexpr float DLOG2PI = 3763.9722f; // D * log(2*pi)

// GEMM tiling: 128x144 tile, BK=64 (8 x 16B chunks per row, XOR-swizzled)
constexpr int BM = 128, BN = 144, BK = 64;

// Workspace layout (bytes)
constexpr size_t OFF_PSI   = 0;          // psi_inv: D*4
constexpr size_t OFF_LDP   = 8192;       // logdetPsi scalar
constexpr size_t OFF_LOGPI = 8448;       // K*4
constexpr size_t OFF_OFFK  = 10752;      // K*4
constexpr size_t OFF_MINV  = 13056;      // K*64*4
constexpr size_t OFF_XPX   = 144384;     // B*4
constexpr size_t OFF_XBF   = 177408;     // B*D*2
constexpr size_t OFF_GT    = 33731840;   // N*D*2  (Gt[n][d], k-contig rows)
constexpr size_t OFF_LL    = 52606208;   // B*K*4
constexpr size_t OFF_PART  = 69383424;   // 2048*4

typedef __bf16 bf16x8 __attribute__((ext_vector_type(8)));
typedef float f32x4 __attribute__((ext_vector_type(4)));

__device__ inline float softplusf(float x) {
  return fmaxf(x, 0.f) + log1pf(expf(-fabsf(x)));
}
__device__ inline unsigned short f2bf(float x) {
  unsigned int u = __builtin_bit_cast(unsigned int, x);
  u = (u + 0x7fffu + ((u >> 16) & 1u)) >> 16;
  return (unsigned short)u;
}
__device__ inline unsigned int pack2(float a, float b) {
  return (unsigned int)f2bf(a) | ((unsigned int)f2bf(b) << 16);
}
// async global->LDS, 16B per lane; LDS dest is wave-uniform base + lane*16
__device__ inline void glds16(const unsigned short* g, char* l) {
  __builtin_amdgcn_global_load_lds(
      (const __attribute__((address_space(1))) unsigned int*)g,
      (__attribute__((address_space(3))) unsigned int*)l, 16, 0, 0);
}

// ---------------- Kernel A: psi, logdetPsi, log_pi ----------------
__global__ __launch_bounds__(256) void prep_psi(
    const float* __restrict__ psi_rho, const float* __restrict__ pi_logits,
    float* __restrict__ psi_inv, float* __restrict__ logdetPsi,
    float* __restrict__ logpi) {
  __shared__ float red[256];
  int t = threadIdx.x;
  float acc = 0.f;
  for (int d = t; d < Dd; d += 256) {
    float p = softplusf(psi_rho[d]) + 1e-5f;
    psi_inv[d] = 1.f / p;
    acc += logf(p);
  }
  red[t] = acc;
  __syncthreads();
  for (int s = 128; s > 0; s >>= 1) { if (t < s) red[t] += red[t + s]; __syncthreads(); }
  if (t == 0) *logdetPsi = red[0];
  __syncthreads();
  float mx = -3.4e38f;
  for (int i = t; i < Kk; i += 256) mx = fmaxf(mx, pi_logits[i]);
  red[t] = mx;
  __syncthreads();
  for (int s = 128; s > 0; s >>= 1) { if (t < s) red[t] = fmaxf(red[t], red[t + s]); __syncthreads(); }
  mx = red[0];
  __syncthreads();
  float se = 0.f;
  for (int i = t; i < Kk; i += 256) se += expf(pi_logits[i] - mx);
  red[t] = se;
  __syncthreads();
  for (int s = 128; s > 0; s >>= 1) { if (t < s) red[t] += red[t + s]; __syncthreads(); }
  float lse = mx + logf(red[0]);
  for (int i = t; i < Kk; i += 256) logpi[i] = pi_logits[i] - lse;
}

// ---------------- Kernel B: per-component precompute + G columns ----------------
__global__ __launch_bounds__(256) void prep_k(
    const float* __restrict__ mu, const float* __restrict__ dir_raw,
    const float* __restrict__ scale_rho, const float* __restrict__ psi_inv,
    const float* __restrict__ logdetPsi, const float* __restrict__ logpi,
    float* __restrict__ offk, float* __restrict__ Minv,
    unsigned short* __restrict__ Gt) {
  int k = blockIdx.x, t = threadIdx.x, lane = t & 63, w = t >> 6;
  float vals[53];
#pragma unroll
  for (int i = 0; i < 53; i++) vals[i] = 0.f;
  const float4* dirp = (const float4*)(dir_raw + (size_t)k * Dd * Qq);
  for (int d = t; d < Dd; d += 256) {
    float4 da = dirp[d * 2], db = dirp[d * 2 + 1];
    float dir8[8] = {da.x, da.y, da.z, da.w, db.x, db.y, db.z, db.w};
    float pw = psi_inv[d];
    float md = mu[(size_t)k * Dd + d];
    int c = 0;
#pragma unroll
    for (int i = 0; i < 8; i++) {
      float dip = dir8[i] * pw;
#pragma unroll
      for (int j = i; j < 8; j++) { vals[c] += dip * dir8[j]; c++; }
    }
#pragma unroll
    for (int q = 0; q < 8; q++) vals[36 + q] += dir8[q] * dir8[q];
    float mp = md * pw;
#pragma unroll
    for (int q = 0; q < 8; q++) vals[44 + q] += mp * dir8[q];
    vals[52] += md * mp;
  }
  __shared__ float redk[4 * 53];
#pragma unroll
  for (int v = 0; v < 53; v++) {
    float val = vals[v];
#pragma unroll
    for (int o = 32; o; o >>= 1) val += __shfl_down(val, o, 64);
    if (lane == 0) redk[w * 53 + v] = val;
  }
  __syncthreads();
  __shared__ float R[53];
  __shared__ float sAl[8], sHh[8];
  if (t < 53) R[t] = redk[t] + redk[53 + t] + redk[106 + t] + redk[159 + t];
  __syncthreads();
  if (t == 0) {
    float Sf[8][8];
    {
      int c2 = 0;
      for (int i = 0; i < 8; i++)
        for (int j = i; j < 8; j++) { float v = R[c2++]; Sf[i][j] = v; Sf[j][i] = v; }
    }
    float alpha[8];
    for (int q = 0; q < 8; q++) {
      float nr = fmaxf(sqrtf(R[36 + q]), 1e-5f);
      alpha[q] = softplusf(scale_rho[(size_t)k * 8 + q]) / nr;
    }
    float Mm[8][8];
    for (int i = 0; i < 8; i++)
      for (int j = 0; j < 8; j++)
        Mm[i][j] = alpha[i] * alpha[j] * Sf[i][j] + (i == j ? 1.f : 0.f);
    float L[8][8] = {};
    for (int i = 0; i < 8; i++) {
      for (int j = 0; j <= i; j++) {
        float s2 = Mm[i][j];
        for (int p = 0; p < j; p++) s2 -= L[i][p] * L[j][p];
        if (i == j) L[i][i] = sqrtf(s2);
        else        L[i][j] = s2 / L[j][j];
      }
    }
    float logdetM = 0.f;
    for (int i = 0; i < 8; i++) logdetM += 2.f * logf(L[i][i]);
    float wv[8];
    for (int q = 0; q < 8; q++) wv[q] = alpha[q] * R[44 + q];
    float y[8], h[8];
    for (int i = 0; i < 8; i++) {
      float s2 = wv[i];
      for (int p = 0; p < i; p++) s2 -= L[i][p] * y[p];
      y[i] = s2 / L[i][i];
    }
    for (int i = 7; i >= 0; i--) {
      float s2 = y[i];
      for (int p = i + 1; p < 8; p++) s2 -= L[p][i] * h[p];
      h[i] = s2 / L[i][i];
    }
    float cc = R[52];
    for (int q = 0; q < 8; q++) cc -= wv[q] * h[q];
    for (int col = 0; col < 8; col++) {
      float yy[8], z[8];
      for (int i = 0; i < 8; i++) {
        float s2 = (i == col) ? 1.f : 0.f;
        for (int p = 0; p < i; p++) s2 -= L[i][p] * yy[p];
        yy[i] = s2 / L[i][i];
      }
      for (int i = 7; i >= 0; i--) {
        float s2 = yy[i];
        for (int p = i + 1; p < 8; p++) s2 -= L[p][i] * z[p];
        z[i] = s2 / L[i][i];
      }
      for (int r2 = 0; r2 < 8; r2++) Minv[(size_t)k * 64 + r2 * 8 + col] = z[r2];
    }
    offk[k] = -0.5f * (DLOG2PI + logdetPsi[0] + logdetM + cc) + logpi[k];
    for (int q = 0; q < 8; q++) { sAl[q] = alpha[q]; sHh[q] = h[q]; }
  }
  __syncthreads();
  float al[8], hh[8];
#pragma unroll
  for (int q = 0; q < 8; q++) { al[q] = sAl[q]; hh[q] = sHh[q]; }
  // Pass 2: write Gt rows (k*9+q): q<8 -> psi_inv*W col; q=8 -> g = psi_inv*(mu - W h)
  for (int d = t; d < Dd; d += 256) {
    float4 da = dirp[d * 2], db = dirp[d * 2 + 1];
    float dir8[8] = {da.x, da.y, da.z, da.w, db.x, db.y, db.z, db.w};
    float pw = psi_inv[d];
    float md = mu[(size_t)k * Dd + d];
    float gs = 0.f;
#pragma unroll
    for (int q = 0; q < 8; q++) {
      Gt[((size_t)(k * 9 + q)) * Dd + d] = f2bf(pw * al[q] * dir8[q]);
      gs += al[q] * dir8[q] * hh[q];
    }
    Gt[((size_t)(k * 9 + 8)) * Dd + d] = f2bf(pw * (md - gs));
  }
}

// ---------------- Kernel C: x -> bf16, xT Psi^-1 x ----------------
__global__ __launch_bounds__(256) void prep_x(
    const float* __restrict__ x, const float* __restrict__ psi_inv,
    unsigned short* __restrict__ xbf, float* __restrict__ xPx) {
  int b = blockIdx.x, t = threadIdx.x, lane = t & 63, w = t >> 6;
  const float4* xr = (const float4*)(x + (size_t)b * Dd);
  const float4* pr = (const float4*)psi_inv;
  float4 v0 = xr[2 * t], v1 = xr[2 * t + 1];
  float4 p0 = pr[2 * t], p1 = pr[2 * t + 1];
  float acc = v0.x * v0.x * p0.x + v0.y * v0.y * p0.y + v0.z * v0.z * p0.z + v0.w * v0.w * p0.w
            + v1.x * v1.x * p1.x + v1.y * v1.y * p1.y + v1.z * v1.z * p1.z + v1.w * v1.w * p1.w;
  uint4 o;
  o.x = pack2(v0.x, v0.y); o.y = pack2(v0.z, v0.w);
  o.z = pack2(v1.x, v1.y); o.w = pack2(v1.z, v1.w);
  *(uint4*)(xbf + (size_t)b * Dd + t * 8) = o;
#pragma unroll
  for (int s2 = 32; s2; s2 >>= 1) acc += __shfl_down(acc, s2, 64);
  __shared__ float r4[4];
  if (lane == 0) r4[w] = acc;
  __syncthreads();
  if (t == 0) xPx[b] = r4[0] + r4[1] + r4[2] + r4[3];
}

// ---------------- Kernel D: fused GEMM + ll epilogue ----------------
// LDS: staging As 128x(8x16B)=16384 | Bs 144x(8x16B)=18432  (union with Cs)
//      Cs epilogue: 4 waves x 16 x 148 f32 = 37888
//      sMinv 4096 | sOff 64  -> total 42048
__global__ __launch_bounds__(256, 3) void gemm_ll(
    const unsigned short* __restrict__ xbf, const unsigned short* __restrict__ Gt,
    const float* __restrict__ Minv, const float* __restrict__ offk,
    const float* __restrict__ xPx, float* __restrict__ ll) {
  __shared__ char smem[42048];
  unsigned short* As = (unsigned short*)smem;            // [128][64] bf16, swizzled chunks
  unsigned short* Bs = (unsigned short*)(smem + 16384);  // [144][64] bf16, swizzled chunks
  float* Cs    = (float*)smem;                           // [4][16][148] f32 (union)
  float* sMinv = (float*)(smem + 37888);                 // [16][64]
  float* sOff  = (float*)(smem + 37888 + 4096);          // [16]

  int t = threadIdx.x, lane = t & 63, w = t >> 6;
  int m0 = blockIdx.y * BM;
  int n0 = blockIdx.x * BN;
  int comp0 = blockIdx.x * 16;

  for (int i = t; i < 1024; i += 256) sMinv[i] = Minv[(size_t)comp0 * 64 + i];
  if (t < 16) sOff[t] = offk[comp0 + t];

  f32x4 acc[2][9];
  f32x4 zero = {0.f, 0.f, 0.f, 0.f};
#pragma unroll
  for (int mt = 0; mt < 2; mt++)
#pragma unroll
    for (int nt = 0; nt < 9; nt++) acc[mt][nt] = zero;

  // staging geometry: each 1KB wave-load covers 8 rows x 8 chunks of 16B
  int rr  = lane >> 3;        // row within 8-row group (also r&7 of the dest row)
  int cph = lane & 7;         // physical chunk slot in LDS
  int csw = cph ^ rr;         // swizzled global chunk index
  // fragment-read geometry
  int quad = lane >> 4, r16 = lane & 15;
  int aswz = r16 & 7;

  for (int k0 = 0; k0 < Dd; k0 += BK) {
    __syncthreads();  // previous iteration's reads done before overwriting LDS
    // A tile: 16 wave-loads; wave w stages its own 32 rows (j = 4w..4w+3)
#pragma unroll
    for (int j = 0; j < 4; ++j) {
      int jj = w * 4 + j;
      glds16(xbf + (size_t)(m0 + jj * 8 + rr) * Dd + k0 + csw * 8,
             smem + jj * 1024);
    }
    // B tile: 18 wave-loads round-robin
    for (int jj = w; jj < 18; jj += 4) {
      glds16(Gt + (size_t)(n0 + jj * 8 + rr) * Dd + k0 + csw * 8,
             smem + 16384 + jj * 1024);
    }
    __syncthreads();  // compiler drains vmcnt(0) here (glds completion)
#pragma unroll
    for (int kh = 0; kh < 2; ++kh) {
      int phys = (kh * 4 + quad) ^ aswz;  // swizzled chunk to read
      bf16x8 a0 = *(const bf16x8*)(As + (w * 32 + r16) * 64 + phys * 8);
      bf16x8 a1 = *(const bf16x8*)(As + (w * 32 + 16 + r16) * 64 + phys * 8);
#pragma unroll
      for (int nt = 0; nt < 9; ++nt) {
        bf16x8 bfr = *(const bf16x8*)(Bs + (nt * 16 + r16) * 64 + phys * 8);
        acc[0][nt] = __builtin_amdgcn_mfma_f32_16x16x32_bf16(a0, bfr, acc[0][nt], 0, 0, 0);
        acc[1][nt] = __builtin_amdgcn_mfma_f32_16x16x32_bf16(a1, bfr, acc[1][nt], 0, 0, 0);
      }
    }
  }

  // Epilogue: per wave, round-trip its 16x144 sub-tile through LDS (stride 148)
  float* myC = Cs + w * (16 * 148);
#pragma unroll
  for (int mt = 0; mt < 2; ++mt) {
    __syncthreads();
#pragma unroll
    for (int nt = 0; nt < 9; ++nt) {
#pragma unroll
      for (int r = 0; r < 4; r++) {
        myC[(quad * 4 + r) * 148 + nt * 16 + r16] = acc[mt][nt][r];
      }
    }
    __syncthreads();
#pragma unroll
    for (int i = 0; i < 4; i++) {
      int cell = lane + 64 * i;
      int row_l = cell >> 4, cl = cell & 15;
      int b = m0 + w * 32 + mt * 16 + row_l;
      const float* cp = myC + row_l * 148 + cl * 9;
      float u[8];
#pragma unroll
      for (int j = 0; j < 8; j++) u[j] = cp[j];
      float s = cp[8];
      const float* Mi = sMinv + cl * 64;
      float tq = 0.f;
#pragma unroll
      for (int a2 = 0; a2 < 8; a2++) {
#pragma unroll
        for (int b2 = 0; b2 < 8; b2++) tq += u[a2] * Mi[a2 * 8 + b2] * u[b2];
      }
      ll[(size_t)b * Kk + comp0 + cl] = sOff[cl] + s + 0.5f * tq - 0.5f * xPx[b];
    }
  }
}

// ---------------- Kernel E1: logsumexp per row -> block partials ----------------
__global__ __launch_bounds__(256) void lse_rows(
    const float* __restrict__ ll, float* __restrict__ part) {
  int t = threadIdx.x, lane = t & 63, w = t >> 6;
  int b = blockIdx.x * 4 + w;
  const float* row = ll + (size_t)b * Kk;
  float v[8];
  float mx = -3.4e38f;
#pragma unroll
  for (int i = 0; i < 8; i++) { v[i] = row[lane + 64 * i]; mx = fmaxf(mx, v[i]); }
#pragma unroll
  for (int o = 32; o; o >>= 1) mx = fmaxf(mx, __shfl_xor(mx, o, 64));
  float se = 0.f;
#pragma unroll
  for (int i = 0; i < 8; i++) se += expf(v[i] - mx);
#pragma unroll
  for (int o = 32; o; o >>= 1) se += __shfl_xor(se, o, 64);
  __shared__ float r4[4];
  if (lane == 0) r4[w] = -(mx + logf(se));
  __syncthreads();
  if (t == 0) part[blockIdx.x] = r4[0] + r4[1] + r4[2] + r4[3];
}

// ---------------- Kernel E2: final mean ----------------
__global__ __launch_bounds__(256) void final_mean(
    const float* __restrict__ part, float* __restrict__ out) {
  int t = threadIdx.x, lane = t & 63, w = t >> 6;
  float acc = 0.f;
  for (int i = t; i < 2048; i += 256) acc += part[i];
#pragma unroll
  for (int o = 32; o; o >>= 1) acc += __shfl_down(acc, o, 64);
  __shared__ float r4[4];
  if (lane == 0) r4[w] = acc;
  __syncthreads();
  if (t == 0) out[0] = (r4[0] + r4[1] + r4[2] + r4[3]) * (1.0f / 8192.0f);
}

extern "C" void kernel_launch(void* const* d_in, const int* in_sizes, int n_in,
                              void* d_out, int out_size, void* d_ws, size_t ws_size,
                              hipStream_t stream) {
  const float* x         = (const float*)d_in[0];
  const float* mu        = (const float*)d_in[1];
  const float* dir_raw   = (const float*)d_in[2];
  const float* scale_rho = (const float*)d_in[3];
  const float* psi_rho   = (const float*)d_in[4];
  const float* pi_logits = (const float*)d_in[5];
  float* out = (float*)d_out;
  char* ws = (char*)d_ws;

  float* psi_inv          = (float*)(ws + OFF_PSI);
  float* logdetPsi        = (float*)(ws + OFF_LDP);
  float* logpi            = (float*)(ws + OFF_LOGPI);
  float* offk             = (float*)(ws + OFF_OFFK);
  float* Minv             = (float*)(ws + OFF_MINV);
  float* xPx              = (float*)(ws + OFF_XPX);
  unsigned short* xbf     = (unsigned short*)(ws + OFF_XBF);
  unsigned short* Gt      = (unsigned short*)(ws + OFF_GT);
  float* ll               = (float*)(ws + OFF_LL);
  float* part             = (float*)(ws + OFF_PART);

  prep_psi<<<1, 256, 0, stream>>>(psi_rho, pi_logits, psi_inv, logdetPsi, logpi);
  prep_k<<<Kk, 256, 0, stream>>>(mu, dir_raw, scale_rho, psi_inv, logdetPsi, logpi,
                                 offk, Minv, Gt);
  prep_x<<<Bn, 256, 0, stream>>>(x, psi_inv, xbf, xPx);
  dim3 g(Nn / BN, Bn / BM);  // (32, 64)
  gemm_ll<<<g, 256, 0, stream>>>(xbf, Gt, Minv, offk, xPx, ll);
  lse_rows<<<Bn / 4, 256, 0, stream>>>(ll, part);
  final_mean<<<1, 256, 0, stream>>>(part, out);
}

// Round 3
// 327.341 us; speedup vs baseline: 3.0200x; 1.6599x over previous
//
#include <hip/hip_runtime.h>

// Problem constants
constexpr int Bn = 8192;   // batch
constexpr int Dd = 2048;   // dims
constexpr int Kk = 512;    // components
constexpr int Qq = 8;      // factors
constexpr int Nn = Kk * 9; // GEMM N: 8 PinvW cols + 1 g col per component = 4608
constexpr float DLOG2PI = 3763.9722f; // D * log(2*pi)

// GEMM tiling: 128x144 tile, BK=64 (8 x 16B chunks per row, XOR-swizzled)
constexpr int BM = 128, BN = 144, BK = 64;

// Workspace layout (bytes)
constexpr size_t OFF_PSI   = 0;          // psi_inv: D*4
constexpr size_t OFF_LDP   = 8192;       // logdetPsi scalar
constexpr size_t OFF_LOGPI = 8448;       // K*4
constexpr size_t OFF_OFFK  = 10752;      // K*4
constexpr size_t OFF_MINV  = 13056;      // K*64*4
constexpr size_t OFF_XPX   = 144384;     // B*4
constexpr size_t OFF_XBF   = 177408;     // B*D*2
constexpr size_t OFF_GT    = 33731840;   // N*D*2  (Gt[n][d], k-contig rows)
constexpr size_t OFF_LL    = 52606208;   // B*K*4
constexpr size_t OFF_PART  = 69383424;   // 2048*4

typedef __bf16 bf16x8 __attribute__((ext_vector_type(8)));
typedef float f32x4 __attribute__((ext_vector_type(4)));

__device__ inline float softplusf(float x) {
  return fmaxf(x, 0.f) + log1pf(expf(-fabsf(x)));
}
__device__ inline unsigned short f2bf(float x) {
  unsigned int u = __builtin_bit_cast(unsigned int, x);
  u = (u + 0x7fffu + ((u >> 16) & 1u)) >> 16;
  return (unsigned short)u;
}
__device__ inline unsigned int pack2(float a, float b) {
  return (unsigned int)f2bf(a) | ((unsigned int)f2bf(b) << 16);
}
// async global->LDS, 16B per lane; LDS dest is wave-uniform base + lane*16
__device__ inline void glds16(const unsigned short* g, char* l) {
  __builtin_amdgcn_global_load_lds(
      (const __attribute__((address_space(1))) unsigned int*)g,
      (__attribute__((address_space(3))) unsigned int*)l, 16, 0, 0);
}

// ---------------- Kernel A: psi, logdetPsi, log_pi ----------------
__global__ __launch_bounds__(256) void prep_psi(
    const float* __restrict__ psi_rho, const float* __restrict__ pi_logits,
    float* __restrict__ psi_inv, float* __restrict__ logdetPsi,
    float* __restrict__ logpi) {
  __shared__ float red[256];
  int t = threadIdx.x;
  float acc = 0.f;
  for (int d = t; d < Dd; d += 256) {
    float p = softplusf(psi_rho[d]) + 1e-5f;
    psi_inv[d] = 1.f / p;
    acc += logf(p);
  }
  red[t] = acc;
  __syncthreads();
  for (int s = 128; s > 0; s >>= 1) { if (t < s) red[t] += red[t + s]; __syncthreads(); }
  if (t == 0) *logdetPsi = red[0];
  __syncthreads();
  float mx = -3.4e38f;
  for (int i = t; i < Kk; i += 256) mx = fmaxf(mx, pi_logits[i]);
  red[t] = mx;
  __syncthreads();
  for (int s = 128; s > 0; s >>= 1) { if (t < s) red[t] = fmaxf(red[t], red[t + s]); __syncthreads(); }
  mx = red[0];
  __syncthreads();
  float se = 0.f;
  for (int i = t; i < Kk; i += 256) se += expf(pi_logits[i] - mx);
  red[t] = se;
  __syncthreads();
  for (int s = 128; s > 0; s >>= 1) { if (t < s) red[t] += red[t + s]; __syncthreads(); }
  float lse = mx + logf(red[0]);
  for (int i = t; i < Kk; i += 256) logpi[i] = pi_logits[i] - lse;
}

// ---------------- Kernel B: per-component precompute + G columns ----------------
__global__ __launch_bounds__(256) void prep_k(
    const float* __restrict__ mu, const float* __restrict__ dir_raw,
    const float* __restrict__ scale_rho, const float* __restrict__ psi_inv,
    const float* __restrict__ logdetPsi, const float* __restrict__ logpi,
    float* __restrict__ offk, float* __restrict__ Minv,
    unsigned short* __restrict__ Gt) {
  int k = blockIdx.x, t = threadIdx.x, lane = t & 63, w = t >> 6;
  float vals[53];
#pragma unroll
  for (int i = 0; i < 53; i++) vals[i] = 0.f;
  const float4* dirp = (const float4*)(dir_raw + (size_t)k * Dd * Qq);
  for (int d = t; d < Dd; d += 256) {
    float4 da = dirp[d * 2], db = dirp[d * 2 + 1];
    float dir8[8] = {da.x, da.y, da.z, da.w, db.x, db.y, db.z, db.w};
    float pw = psi_inv[d];
    float md = mu[(size_t)k * Dd + d];
    int c = 0;
#pragma unroll
    for (int i = 0; i < 8; i++) {
      float dip = dir8[i] * pw;
#pragma unroll
      for (int j = i; j < 8; j++) { vals[c] += dip * dir8[j]; c++; }
    }
#pragma unroll
    for (int q = 0; q < 8; q++) vals[36 + q] += dir8[q] * dir8[q];
    float mp = md * pw;
#pragma unroll
    for (int q = 0; q < 8; q++) vals[44 + q] += mp * dir8[q];
    vals[52] += md * mp;
  }
  __shared__ float redk[4 * 53];
#pragma unroll
  for (int v = 0; v < 53; v++) {
    float val = vals[v];
#pragma unroll
    for (int o = 32; o; o >>= 1) val += __shfl_down(val, o, 64);
    if (lane == 0) redk[w * 53 + v] = val;
  }
  __syncthreads();
  __shared__ float R[53];
  __shared__ float sAl[8], sHh[8];
  if (t < 53) R[t] = redk[t] + redk[53 + t] + redk[106 + t] + redk[159 + t];
  __syncthreads();
  if (t == 0) {
    float Sf[8][8];
    {
      int c2 = 0;
      for (int i = 0; i < 8; i++)
        for (int j = i; j < 8; j++) { float v = R[c2++]; Sf[i][j] = v; Sf[j][i] = v; }
    }
    float alpha[8];
    for (int q = 0; q < 8; q++) {
      float nr = fmaxf(sqrtf(R[36 + q]), 1e-5f);
      alpha[q] = softplusf(scale_rho[(size_t)k * 8 + q]) / nr;
    }
    float Mm[8][8];
    for (int i = 0; i < 8; i++)
      for (int j = 0; j < 8; j++)
        Mm[i][j] = alpha[i] * alpha[j] * Sf[i][j] + (i == j ? 1.f : 0.f);
    float L[8][8] = {};
    for (int i = 0; i < 8; i++) {
      for (int j = 0; j <= i; j++) {
        float s2 = Mm[i][j];
        for (int p = 0; p < j; p++) s2 -= L[i][p] * L[j][p];
        if (i == j) L[i][i] = sqrtf(s2);
        else        L[i][j] = s2 / L[j][j];
      }
    }
    float logdetM = 0.f;
    for (int i = 0; i < 8; i++) logdetM += 2.f * logf(L[i][i]);
    float wv[8];
    for (int q = 0; q < 8; q++) wv[q] = alpha[q] * R[44 + q];
    float y[8], h[8];
    for (int i = 0; i < 8; i++) {
      float s2 = wv[i];
      for (int p = 0; p < i; p++) s2 -= L[i][p] * y[p];
      y[i] = s2 / L[i][i];
    }
    for (int i = 7; i >= 0; i--) {
      float s2 = y[i];
      for (int p = i + 1; p < 8; p++) s2 -= L[p][i] * h[p];
      h[i] = s2 / L[i][i];
    }
    float cc = R[52];
    for (int q = 0; q < 8; q++) cc -= wv[q] * h[q];
    for (int col = 0; col < 8; col++) {
      float yy[8], z[8];
      for (int i = 0; i < 8; i++) {
        float s2 = (i == col) ? 1.f : 0.f;
        for (int p = 0; p < i; p++) s2 -= L[i][p] * yy[p];
        yy[i] = s2 / L[i][i];
      }
      for (int i = 7; i >= 0; i--) {
        float s2 = yy[i];
        for (int p = i + 1; p < 8; p++) s2 -= L[p][i] * z[p];
        z[i] = s2 / L[i][i];
      }
      for (int r2 = 0; r2 < 8; r2++) Minv[(size_t)k * 64 + r2 * 8 + col] = z[r2];
    }
    offk[k] = -0.5f * (DLOG2PI + logdetPsi[0] + logdetM + cc) + logpi[k];
    for (int q = 0; q < 8; q++) { sAl[q] = alpha[q]; sHh[q] = h[q]; }
  }
  __syncthreads();
  float al[8], hh[8];
#pragma unroll
  for (int q = 0; q < 8; q++) { al[q] = sAl[q]; hh[q] = sHh[q]; }
  // Pass 2: write Gt rows (k*9+q): q<8 -> psi_inv*W col; q=8 -> g = psi_inv*(mu - W h)
  for (int d = t; d < Dd; d += 256) {
    float4 da = dirp[d * 2], db = dirp[d * 2 + 1];
    float dir8[8] = {da.x, da.y, da.z, da.w, db.x, db.y, db.z, db.w};
    float pw = psi_inv[d];
    float md = mu[(size_t)k * Dd + d];
    float gs = 0.f;
#pragma unroll
    for (int q = 0; q < 8; q++) {
      Gt[((size_t)(k * 9 + q)) * Dd + d] = f2bf(pw * al[q] * dir8[q]);
      gs += al[q] * dir8[q] * hh[q];
    }
    Gt[((size_t)(k * 9 + 8)) * Dd + d] = f2bf(pw * (md - gs));
  }
}

// ---------------- Kernel C: x -> bf16, xT Psi^-1 x ----------------
__global__ __launch_bounds__(256) void prep_x(
    const float* __restrict__ x, const float* __restrict__ psi_inv,
    unsigned short* __restrict__ xbf, float* __restrict__ xPx) {
  int b = blockIdx.x, t = threadIdx.x, lane = t & 63, w = t >> 6;
  const float4* xr = (const float4*)(x + (size_t)b * Dd);
  const float4* pr = (const float4*)psi_inv;
  float4 v0 = xr[2 * t], v1 = xr[2 * t + 1];
  float4 p0 = pr[2 * t], p1 = pr[2 * t + 1];
  float acc = v0.x * v0.x * p0.x + v0.y * v0.y * p0.y + v0.z * v0.z * p0.z + v0.w * v0.w * p0.w
            + v1.x * v1.x * p1.x + v1.y * v1.y * p1.y + v1.z * v1.z * p1.z + v1.w * v1.w * p1.w;
  uint4 o;
  o.x = pack2(v0.x, v0.y); o.y = pack2(v0.z, v0.w);
  o.z = pack2(v1.x, v1.y); o.w = pack2(v1.z, v1.w);
  *(uint4*)(xbf + (size_t)b * Dd + t * 8) = o;
#pragma unroll
  for (int s2 = 32; s2; s2 >>= 1) acc += __shfl_down(acc, s2, 64);
  __shared__ float r4[4];
  if (lane == 0) r4[w] = acc;
  __syncthreads();
  if (t == 0) xPx[b] = r4[0] + r4[1] + r4[2] + r4[3];
}

// ---------------- Kernel D: fused GEMM + ll epilogue ----------------
// LDS: staging As 128x(8x16B)=16384 | Bs 144x(8x16B)=18432  (union with Cs)
//      Cs epilogue: 4 waves x 16 x 148 f32 = 37888
//      sMinv 16x65x4=4160 (stride 65: bank = cl+idx mod 32, conflict-free)
//      sOff 64 -> total 42112
__global__ __launch_bounds__(256, 3) void gemm_ll(
    const unsigned short* __restrict__ xbf, const unsigned short* __restrict__ Gt,
    const float* __restrict__ Minv, const float* __restrict__ offk,
    const float* __restrict__ xPx, float* __restrict__ ll) {
  __shared__ char smem[42112];
  unsigned short* As = (unsigned short*)smem;            // [128][64] bf16, swizzled chunks
  unsigned short* Bs = (unsigned short*)(smem + 16384);  // [144][64] bf16, swizzled chunks
  float* Cs    = (float*)smem;                           // [4][16][148] f32 (union)
  float* sMinv = (float*)(smem + 37888);                 // [16][65]
  float* sOff  = (float*)(smem + 37888 + 4160);          // [16]

  int t = threadIdx.x, lane = t & 63, w = t >> 6;
  int m0 = blockIdx.y * BM;
  int n0 = blockIdx.x * BN;
  int comp0 = blockIdx.x * 16;

  // load Minv into padded-stride LDS
  for (int i = t; i < 1024; i += 256) {
    int cl = i >> 6, idx = i & 63;
    sMinv[cl * 65 + idx] = Minv[(size_t)comp0 * 64 + i];
  }
  if (t < 16) sOff[t] = offk[comp0 + t];

  f32x4 acc[2][9];
  f32x4 zero = {0.f, 0.f, 0.f, 0.f};
#pragma unroll
  for (int mt = 0; mt < 2; mt++)
#pragma unroll
    for (int nt = 0; nt < 9; nt++) acc[mt][nt] = zero;

  // staging geometry: each 1KB wave-load covers 8 rows x 8 chunks of 16B
  int rr  = lane >> 3;        // row within 8-row group (also r&7 of the dest row)
  int cph = lane & 7;         // physical chunk slot in LDS
  int csw = cph ^ rr;         // swizzled global chunk index
  // fragment-read geometry
  int quad = lane >> 4, r16 = lane & 15;
  int aswz = r16 & 7;

  for (int k0 = 0; k0 < Dd; k0 += BK) {
    __syncthreads();  // previous iteration's reads done before overwriting LDS
    // A tile: 16 wave-loads; wave w stages its own 32 rows (j = 4w..4w+3)
#pragma unroll
    for (int j = 0; j < 4; ++j) {
      int jj = w * 4 + j;
      glds16(xbf + (size_t)(m0 + jj * 8 + rr) * Dd + k0 + csw * 8,
             smem + jj * 1024);
    }
    // B tile: 18 wave-loads round-robin
    for (int jj = w; jj < 18; jj += 4) {
      glds16(Gt + (size_t)(n0 + jj * 8 + rr) * Dd + k0 + csw * 8,
             smem + 16384 + jj * 1024);
    }
    __syncthreads();  // compiler drains vmcnt(0) here (glds completion)
#pragma unroll
    for (int kh = 0; kh < 2; ++kh) {
      int phys = (kh * 4 + quad) ^ aswz;  // swizzled chunk to read
      bf16x8 a0 = *(const bf16x8*)(As + (w * 32 + r16) * 64 + phys * 8);
      bf16x8 a1 = *(const bf16x8*)(As + (w * 32 + 16 + r16) * 64 + phys * 8);
#pragma unroll
      for (int nt = 0; nt < 9; ++nt) {
        bf16x8 bfr = *(const bf16x8*)(Bs + (nt * 16 + r16) * 64 + phys * 8);
        acc[0][nt] = __builtin_amdgcn_mfma_f32_16x16x32_bf16(a0, bfr, acc[0][nt], 0, 0, 0);
        acc[1][nt] = __builtin_amdgcn_mfma_f32_16x16x32_bf16(a1, bfr, acc[1][nt], 0, 0, 0);
      }
    }
  }

  // Hoisted Minv upper-triangle for this thread's component (cl = lane&15 is
  // invariant across the epilogue loops). 0.5 folded into the diagonal.
  // Reads: bank = (cl + idx) mod 32 -> 16 distinct banks, quad-broadcast: free.
  float P[36];
  {
    const float* Mi = sMinv + r16 * 65;
    int c = 0;
#pragma unroll
    for (int i2 = 0; i2 < 8; i2++) {
      P[c++] = 0.5f * Mi[i2 * 8 + i2];
#pragma unroll
      for (int j2 = i2 + 1; j2 < 8; j2++) P[c++] = Mi[i2 * 8 + j2];
    }
  }
  float offc = sOff[r16];

  // Epilogue: per wave, round-trip its 16x144 sub-tile through LDS (stride 148)
  float* myC = Cs + w * (16 * 148);
#pragma unroll
  for (int mt = 0; mt < 2; ++mt) {
    __syncthreads();
#pragma unroll
    for (int nt = 0; nt < 9; ++nt) {
#pragma unroll
      for (int r = 0; r < 4; r++) {
        myC[(quad * 4 + r) * 148 + nt * 16 + r16] = acc[mt][nt][r];
      }
    }
    __syncthreads();
#pragma unroll
    for (int i = 0; i < 4; i++) {
      int row_l = quad + 4 * i;       // cell = lane + 64*i: row=cell>>4, cl=lane&15
      int b = m0 + w * 32 + mt * 16 + row_l;
      const float* cp = myC + row_l * 148 + r16 * 9;
      float u[8];
#pragma unroll
      for (int j = 0; j < 8; j++) u[j] = cp[j];
      float s = cp[8];
      float tq = 0.f;
      int c = 0;
#pragma unroll
      for (int i2 = 0; i2 < 8; i2++) {
        float s2 = P[c++] * u[i2];
#pragma unroll
        for (int j2 = i2 + 1; j2 < 8; j2++) s2 += P[c++] * u[j2];
        tq += u[i2] * s2;
      }
      ll[(size_t)b * Kk + comp0 + r16] = offc + s + tq - 0.5f * xPx[b];
    }
  }
}

// ---------------- Kernel E1: logsumexp per row -> block partials ----------------
__global__ __launch_bounds__(256) void lse_rows(
    const float* __restrict__ ll, float* __restrict__ part) {
  int t = threadIdx.x, lane = t & 63, w = t >> 6;
  int b = blockIdx.x * 4 + w;
  const float* row = ll + (size_t)b * Kk;
  float v[8];
  float mx = -3.4e38f;
#pragma unroll
  for (int i = 0; i < 8; i++) { v[i] = row[lane + 64 * i]; mx = fmaxf(mx, v[i]); }
#pragma unroll
  for (int o = 32; o; o >>= 1) mx = fmaxf(mx, __shfl_xor(mx, o, 64));
  float se = 0.f;
#pragma unroll
  for (int i = 0; i < 8; i++) se += expf(v[i] - mx);
#pragma unroll
  for (int o = 32; o; o >>= 1) se += __shfl_xor(se, o, 64);
  __shared__ float r4[4];
  if (lane == 0) r4[w] = -(mx + logf(se));
  __syncthreads();
  if (t == 0) part[blockIdx.x] = r4[0] + r4[1] + r4[2] + r4[3];
}

// ---------------- Kernel E2: final mean ----------------
__global__ __launch_bounds__(256) void final_mean(
    const float* __restrict__ part, float* __restrict__ out) {
  int t = threadIdx.x, lane = t & 63, w = t >> 6;
  float acc = 0.f;
  for (int i = t; i < 2048; i += 256) acc += part[i];
#pragma unroll
  for (int o = 32; o; o >>= 1) acc += __shfl_down(acc, o, 64);
  __shared__ float r4[4];
  if (lane == 0) r4[w] = acc;
  __syncthreads();
  if (t == 0) out[0] = (r4[0] + r4[1] + r4[2] + r4[3]) * (1.0f / 8192.0f);
}

extern "C" void kernel_launch(void* const* d_in, const int* in_sizes, int n_in,
                              void* d_out, int out_size, void* d_ws, size_t ws_size,
                              hipStream_t stream) {
  const float* x         = (const float*)d_in[0];
  const float* mu        = (const float*)d_in[1];
  const float* dir_raw   = (const float*)d_in[2];
  const float* scale_rho = (const float*)d_in[3];
  const float* psi_rho   = (const float*)d_in[4];
  const float* pi_logits = (const float*)d_in[5];
  float* out = (float*)d_out;
  char* ws = (char*)d_ws;

  float* psi_inv          = (float*)(ws + OFF_PSI);
  float* logdetPsi        = (float*)(ws + OFF_LDP);
  float* logpi            = (float*)(ws + OFF_LOGPI);
  float* offk             = (float*)(ws + OFF_OFFK);
  float* Minv             = (float*)(ws + OFF_MINV);
  float* xPx              = (float*)(ws + OFF_XPX);
  unsigned short* xbf     = (unsigned short*)(ws + OFF_XBF);
  unsigned short* Gt      = (unsigned short*)(ws + OFF_GT);
  float* ll               = (float*)(ws + OFF_LL);
  float* part             = (float*)(ws + OFF_PART);

  prep_psi<<<1, 256, 0, stream>>>(psi_rho, pi_logits, psi_inv, logdetPsi, logpi);
  prep_k<<<Kk, 256, 0, stream>>>(mu, dir_raw, scale_rho, psi_inv, logdetPsi, logpi,
                                 offk, Minv, Gt);
  prep_x<<<Bn, 256, 0, stream>>>(x, psi_inv, xbf, xPx);
  dim3 g(Nn / BN, Bn / BM);  // (32, 64)
  gemm_ll<<<g, 256, 0, stream>>>(xbf, Gt, Minv, offk, xPx, ll);
  lse_rows<<<Bn / 4, 256, 0, stream>>>(ll, part);
  final_mean<<<1, 256, 0, stream>>>(part, out);
}

// Round 4
// 318.345 us; speedup vs baseline: 3.1053x; 1.0283x over previous
//
#include <hip/hip_runtime.h>

// Problem constants
constexpr int Bn = 8192;   // batch
constexpr int Dd = 2048;   // dims
constexpr int Kk = 512;    // components
constexpr int Qq = 8;      // factors
constexpr int Nn = Kk * 9; // GEMM N: 8 PinvW cols + 1 g col per component = 4608
constexpr float DLOG2PI = 3763.9722f; // D * log(2*pi)

// GEMM tiling: 128x144 tile, BK=64 (8 x 16B chunks per row, XOR-swizzled)
constexpr int BM = 128, BN = 144, BK = 64;

// Workspace layout (bytes)
constexpr size_t OFF_PSI   = 0;          // psi_inv: D*4
constexpr size_t OFF_LDP   = 8192;       // logdetPsi scalar
constexpr size_t OFF_LOGPI = 8448;       // K*4
constexpr size_t OFF_OFFK  = 10752;      // K*4
constexpr size_t OFF_MINV  = 13056;      // K*64*4
constexpr size_t OFF_XPX   = 144384;     // B*4
constexpr size_t OFF_XBF   = 177408;     // B*D*2
constexpr size_t OFF_GT    = 33731840;   // N*D*2  (Gt[n][d], k-contig rows)
constexpr size_t OFF_LL    = 52606208;   // B*K*4
constexpr size_t OFF_PART  = 69383424;   // 2048*4

typedef __bf16 bf16x8 __attribute__((ext_vector_type(8)));
typedef float f32x4 __attribute__((ext_vector_type(4)));

__device__ inline float softplusf(float x) {
  return fmaxf(x, 0.f) + log1pf(expf(-fabsf(x)));
}
__device__ inline unsigned short f2bf(float x) {
  unsigned int u = __builtin_bit_cast(unsigned int, x);
  u = (u + 0x7fffu + ((u >> 16) & 1u)) >> 16;
  return (unsigned short)u;
}
__device__ inline unsigned int pack2(float a, float b) {
  return (unsigned int)f2bf(a) | ((unsigned int)f2bf(b) << 16);
}
// async global->LDS, 16B per lane; LDS dest is wave-uniform base + lane*16
__device__ inline void glds16(const unsigned short* g, char* l) {
  __builtin_amdgcn_global_load_lds(
      (const __attribute__((address_space(1))) unsigned int*)g,
      (__attribute__((address_space(3))) unsigned int*)l, 16, 0, 0);
}

// ---------------- Kernel A: psi, logdetPsi, log_pi ----------------
__global__ __launch_bounds__(256) void prep_psi(
    const float* __restrict__ psi_rho, const float* __restrict__ pi_logits,
    float* __restrict__ psi_inv, float* __restrict__ logdetPsi,
    float* __restrict__ logpi) {
  __shared__ float red[256];
  int t = threadIdx.x;
  float acc = 0.f;
  for (int d = t; d < Dd; d += 256) {
    float p = softplusf(psi_rho[d]) + 1e-5f;
    psi_inv[d] = 1.f / p;
    acc += logf(p);
  }
  red[t] = acc;
  __syncthreads();
  for (int s = 128; s > 0; s >>= 1) { if (t < s) red[t] += red[t + s]; __syncthreads(); }
  if (t == 0) *logdetPsi = red[0];
  __syncthreads();
  float mx = -3.4e38f;
  for (int i = t; i < Kk; i += 256) mx = fmaxf(mx, pi_logits[i]);
  red[t] = mx;
  __syncthreads();
  for (int s = 128; s > 0; s >>= 1) { if (t < s) red[t] = fmaxf(red[t], red[t + s]); __syncthreads(); }
  mx = red[0];
  __syncthreads();
  float se = 0.f;
  for (int i = t; i < Kk; i += 256) se += expf(pi_logits[i] - mx);
  red[t] = se;
  __syncthreads();
  for (int s = 128; s > 0; s >>= 1) { if (t < s) red[t] += red[t + s]; __syncthreads(); }
  float lse = mx + logf(red[0]);
  for (int i = t; i < Kk; i += 256) logpi[i] = pi_logits[i] - lse;
}

// ---------------- Kernel B: per-component precompute + G columns ----------------
// Serial t==0 section fully unrolled (masked constant-trip loops) so all
// [8][8] arrays live in registers, not scratch.
__global__ __launch_bounds__(256) void prep_k(
    const float* __restrict__ mu, const float* __restrict__ dir_raw,
    const float* __restrict__ scale_rho, const float* __restrict__ psi_inv,
    const float* __restrict__ logdetPsi, const float* __restrict__ logpi,
    float* __restrict__ offk, float* __restrict__ Minv,
    unsigned short* __restrict__ Gt) {
  int k = blockIdx.x, t = threadIdx.x, lane = t & 63, w = t >> 6;
  float vals[53];
#pragma unroll
  for (int i = 0; i < 53; i++) vals[i] = 0.f;
  const float4* dirp = (const float4*)(dir_raw + (size_t)k * Dd * Qq);
  for (int d = t; d < Dd; d += 256) {
    float4 da = dirp[d * 2], db = dirp[d * 2 + 1];
    float dir8[8] = {da.x, da.y, da.z, da.w, db.x, db.y, db.z, db.w};
    float pw = psi_inv[d];
    float md = mu[(size_t)k * Dd + d];
    int c = 0;
#pragma unroll
    for (int i = 0; i < 8; i++) {
      float dip = dir8[i] * pw;
#pragma unroll
      for (int j = 0; j < 8; j++) {
        if (j < i) continue;
        vals[c] += dip * dir8[j]; c++;
      }
    }
#pragma unroll
    for (int q = 0; q < 8; q++) vals[36 + q] += dir8[q] * dir8[q];
    float mp = md * pw;
#pragma unroll
    for (int q = 0; q < 8; q++) vals[44 + q] += mp * dir8[q];
    vals[52] += md * mp;
  }
  __shared__ float redk[4 * 53];
#pragma unroll
  for (int v = 0; v < 53; v++) {
    float val = vals[v];
#pragma unroll
    for (int o = 32; o; o >>= 1) val += __shfl_down(val, o, 64);
    if (lane == 0) redk[w * 53 + v] = val;
  }
  __syncthreads();
  __shared__ float R[53];
  __shared__ float sAl[8], sHh[8];
  if (t < 53) R[t] = redk[t] + redk[53 + t] + redk[106 + t] + redk[159 + t];
  __syncthreads();
  if (t == 0) {
    float Sf[8][8];
    {
      int c2 = 0;
#pragma unroll
      for (int i = 0; i < 8; i++) {
#pragma unroll
        for (int j = 0; j < 8; j++) {
          if (j < i) continue;
          float v = R[c2++]; Sf[i][j] = v; Sf[j][i] = v;
        }
      }
    }
    float alpha[8];
#pragma unroll
    for (int q = 0; q < 8; q++) {
      float nr = fmaxf(sqrtf(R[36 + q]), 1e-5f);
      alpha[q] = softplusf(scale_rho[(size_t)k * 8 + q]) / nr;
    }
    float Mm[8][8];
#pragma unroll
    for (int i = 0; i < 8; i++)
#pragma unroll
      for (int j = 0; j < 8; j++)
        Mm[i][j] = alpha[i] * alpha[j] * Sf[i][j] + (i == j ? 1.f : 0.f);
    float L[8][8], Ld[8];
#pragma unroll
    for (int i = 0; i < 8; i++) {
#pragma unroll
      for (int j = 0; j < 8; j++) {
        if (j > i) continue;
        float s2 = Mm[i][j];
#pragma unroll
        for (int p = 0; p < 8; p++) { if (p < j) s2 -= L[i][p] * L[j][p]; }
        if (i == j) { L[i][i] = sqrtf(s2); Ld[i] = 1.f / L[i][i]; }
        else        L[i][j] = s2 * Ld[j];
      }
    }
    float logdetM = 0.f;
#pragma unroll
    for (int i = 0; i < 8; i++) logdetM += 2.f * logf(L[i][i]);
    float wv[8];
#pragma unroll
    for (int q = 0; q < 8; q++) wv[q] = alpha[q] * R[44 + q];
    float y[8], h[8];
#pragma unroll
    for (int i = 0; i < 8; i++) {
      float s2 = wv[i];
#pragma unroll
      for (int p = 0; p < 8; p++) { if (p < i) s2 -= L[i][p] * y[p]; }
      y[i] = s2 * Ld[i];
    }
#pragma unroll
    for (int i = 7; i >= 0; i--) {
      float s2 = y[i];
#pragma unroll
      for (int p = 0; p < 8; p++) { if (p > i) s2 -= L[p][i] * h[p]; }
      h[i] = s2 * Ld[i];
    }
    float cc = R[52];
#pragma unroll
    for (int q = 0; q < 8; q++) cc -= wv[q] * h[q];
#pragma unroll
    for (int col = 0; col < 8; col++) {
      float yy[8], z[8];
#pragma unroll
      for (int i = 0; i < 8; i++) {
        float s2 = (i == col) ? 1.f : 0.f;
#pragma unroll
        for (int p = 0; p < 8; p++) { if (p < i) s2 -= L[i][p] * yy[p]; }
        yy[i] = s2 * Ld[i];
      }
#pragma unroll
      for (int i = 7; i >= 0; i--) {
        float s2 = yy[i];
#pragma unroll
        for (int p = 0; p < 8; p++) { if (p > i) s2 -= L[p][i] * z[p]; }
        z[i] = s2 * Ld[i];
      }
#pragma unroll
      for (int r2 = 0; r2 < 8; r2++) Minv[(size_t)k * 64 + r2 * 8 + col] = z[r2];
    }
    offk[k] = -0.5f * (DLOG2PI + logdetPsi[0] + logdetM + cc) + logpi[k];
#pragma unroll
    for (int q = 0; q < 8; q++) { sAl[q] = alpha[q]; sHh[q] = h[q]; }
  }
  __syncthreads();
  float al[8], hh[8];
#pragma unroll
  for (int q = 0; q < 8; q++) { al[q] = sAl[q]; hh[q] = sHh[q]; }
  // Pass 2: write Gt rows (k*9+q): q<8 -> psi_inv*W col; q=8 -> g = psi_inv*(mu - W h)
  for (int d = t; d < Dd; d += 256) {
    float4 da = dirp[d * 2], db = dirp[d * 2 + 1];
    float dir8[8] = {da.x, da.y, da.z, da.w, db.x, db.y, db.z, db.w};
    float pw = psi_inv[d];
    float md = mu[(size_t)k * Dd + d];
    float gs = 0.f;
#pragma unroll
    for (int q = 0; q < 8; q++) {
      Gt[((size_t)(k * 9 + q)) * Dd + d] = f2bf(pw * al[q] * dir8[q]);
      gs += al[q] * dir8[q] * hh[q];
    }
    Gt[((size_t)(k * 9 + 8)) * Dd + d] = f2bf(pw * (md - gs));
  }
}

// ---------------- Kernel C: x -> bf16, xT Psi^-1 x ----------------
__global__ __launch_bounds__(256) void prep_x(
    const float* __restrict__ x, const float* __restrict__ psi_inv,
    unsigned short* __restrict__ xbf, float* __restrict__ xPx) {
  int b = blockIdx.x, t = threadIdx.x, lane = t & 63, w = t >> 6;
  const float4* xr = (const float4*)(x + (size_t)b * Dd);
  const float4* pr = (const float4*)psi_inv;
  float4 v0 = xr[2 * t], v1 = xr[2 * t + 1];
  float4 p0 = pr[2 * t], p1 = pr[2 * t + 1];
  float acc = v0.x * v0.x * p0.x + v0.y * v0.y * p0.y + v0.z * v0.z * p0.z + v0.w * v0.w * p0.w
            + v1.x * v1.x * p1.x + v1.y * v1.y * p1.y + v1.z * v1.z * p1.z + v1.w * v1.w * p1.w;
  uint4 o;
  o.x = pack2(v0.x, v0.y); o.y = pack2(v0.z, v0.w);
  o.z = pack2(v1.x, v1.y); o.w = pack2(v1.z, v1.w);
  *(uint4*)(xbf + (size_t)b * Dd + t * 8) = o;
#pragma unroll
  for (int s2 = 32; s2; s2 >>= 1) acc += __shfl_down(acc, s2, 64);
  __shared__ float r4[4];
  if (lane == 0) r4[w] = acc;
  __syncthreads();
  if (t == 0) xPx[b] = r4[0] + r4[1] + r4[2] + r4[3];
}

// ---------------- Kernel D: fused GEMM + ll epilogue ----------------
// Wave partition: 2x2 over the 8x9 (Mtile x Ntile) grid.
//   wm = w>>1: rows wm*64..wm*64+63 (4 M-tiles)
//   wn = w&1 : nt 0..4 (wn=0, 80 cols) or nt 5..8 (wn=1, 64 cols)
// Per kh per block: frag reads 34 (vs 44 for 4x(2,9)) -> LDS-read bound eased.
// LDS: staging As 16384 + Bs 18432 = 34816 (union with Cs 32x148x4=18944)
//      sMinv 16x65x4=4160 at 34816 | sOff at 38976 -> total 39040
__global__ __launch_bounds__(256, 3) void gemm_ll(
    const unsigned short* __restrict__ xbf, const unsigned short* __restrict__ Gt,
    const float* __restrict__ Minv, const float* __restrict__ offk,
    const float* __restrict__ xPx, float* __restrict__ ll) {
  __shared__ char smem[39040];
  unsigned short* As = (unsigned short*)smem;            // [128][64] bf16, swizzled chunks
  unsigned short* Bs = (unsigned short*)(smem + 16384);  // [144][64] bf16, swizzled chunks
  float* Cs    = (float*)smem;                           // [32][148] f32 (union w/ staging)
  float* sMinv = (float*)(smem + 34816);                 // [16][65]
  float* sOff  = (float*)(smem + 34816 + 4160);          // [16]

  int t = threadIdx.x, lane = t & 63, w = t >> 6;
  int m0 = blockIdx.y * BM;
  int n0 = blockIdx.x * BN;
  int comp0 = blockIdx.x * 16;

  // load Minv into padded-stride LDS
  for (int i = t; i < 1024; i += 256) {
    int cl = i >> 6, idx = i & 63;
    sMinv[cl * 65 + idx] = Minv[(size_t)comp0 * 64 + i];
  }
  if (t < 16) sOff[t] = offk[comp0 + t];

  int wm = w >> 1, wn = w & 1;
  int nbase = wn * 5;   // starting nt for this wave

  f32x4 acc[4][5];
  f32x4 zero = {0.f, 0.f, 0.f, 0.f};
#pragma unroll
  for (int mt = 0; mt < 4; mt++)
#pragma unroll
    for (int nt = 0; nt < 5; nt++) acc[mt][nt] = zero;

  // staging geometry: each 1KB wave-load covers 8 rows x 8 chunks of 16B
  int rr  = lane >> 3;        // row within 8-row group (also r&7 of the dest row)
  int cph = lane & 7;         // physical chunk slot in LDS
  int csw = cph ^ rr;         // swizzled global chunk index
  // fragment-read geometry
  int quad = lane >> 4, r16 = lane & 15;
  int aswz = r16 & 7;

  for (int k0 = 0; k0 < Dd; k0 += BK) {
    __syncthreads();  // previous iteration's reads done before overwriting LDS
    // A tile: 16 wave-loads; wave w stages its own 32 rows (j = 4w..4w+3)
#pragma unroll
    for (int j = 0; j < 4; ++j) {
      int jj = w * 4 + j;
      glds16(xbf + (size_t)(m0 + jj * 8 + rr) * Dd + k0 + csw * 8,
             smem + jj * 1024);
    }
    // B tile: 18 wave-loads round-robin
    for (int jj = w; jj < 18; jj += 4) {
      glds16(Gt + (size_t)(n0 + jj * 8 + rr) * Dd + k0 + csw * 8,
             smem + 16384 + jj * 1024);
    }
    __syncthreads();  // compiler drains vmcnt(0) here (glds completion)
#pragma unroll
    for (int kh = 0; kh < 2; ++kh) {
      int phys = (kh * 4 + quad) ^ aswz;  // swizzled chunk to read
      bf16x8 av[4];
#pragma unroll
      for (int mtt = 0; mtt < 4; ++mtt)
        av[mtt] = *(const bf16x8*)(As + (wm * 64 + mtt * 16 + r16) * 64 + phys * 8);
#pragma unroll
      for (int ntl = 0; ntl < 5; ++ntl) {
        if (wn == 0 || ntl < 4) {  // wave-uniform guard; only ntl==4 branches
          bf16x8 bfr = *(const bf16x8*)(Bs + ((nbase + ntl) * 16 + r16) * 64 + phys * 8);
#pragma unroll
          for (int mtt = 0; mtt < 4; ++mtt)
            acc[mtt][ntl] = __builtin_amdgcn_mfma_f32_16x16x32_bf16(av[mtt], bfr, acc[mtt][ntl], 0, 0, 0);
        }
      }
    }
  }

  // Hoisted Minv upper-triangle for this thread's component (comp = t&15 = r16,
  // invariant across epilogue loops). 0.5 folded into the diagonal.
  float P[36];
  {
    const float* Mi = sMinv + r16 * 65;
    int c = 0;
#pragma unroll
    for (int i2 = 0; i2 < 8; i2++) {
      P[c++] = 0.5f * Mi[i2 * 8 + i2];
#pragma unroll
      for (int j2 = i2 + 1; j2 < 8; j2++) P[c++] = Mi[i2 * 8 + j2];
    }
  }
  float offc = sOff[r16];

  // Epilogue: 4 phases (one per 16-row group). Both n-waves of a row-group
  // deposit into the shared 32x148 Cs, then all threads read 9-col groups.
#pragma unroll
  for (int mt = 0; mt < 4; ++mt) {
    __syncthreads();
#pragma unroll
    for (int ntl = 0; ntl < 5; ++ntl) {
      if (wn == 0 || ntl < 4) {
#pragma unroll
        for (int r = 0; r < 4; r++) {
          Cs[(wm * 16 + quad * 4 + r) * 148 + (nbase + ntl) * 16 + r16] = acc[mt][ntl][r];
        }
      }
    }
    __syncthreads();
#pragma unroll
    for (int half = 0; half < 2; half++) {
      int row_l = t >> 4;                 // 0..15
      int crow = half * 16 + row_l;
      int b = m0 + half * 64 + mt * 16 + row_l;
      const float* cp = Cs + crow * 148 + (t & 15) * 9;
      float u[8];
#pragma unroll
      for (int j = 0; j < 8; j++) u[j] = cp[j];
      float s = cp[8];
      float tq = 0.f;
      int c = 0;
#pragma unroll
      for (int i2 = 0; i2 < 8; i2++) {
        float s2 = P[c++] * u[i2];
#pragma unroll
        for (int j2 = i2 + 1; j2 < 8; j2++) s2 += P[c++] * u[j2];
        tq += u[i2] * s2;
      }
      ll[(size_t)b * Kk + comp0 + (t & 15)] = offc + s + tq - 0.5f * xPx[b];
    }
  }
}

// ---------------- Kernel E1: logsumexp per row -> block partials ----------------
__global__ __launch_bounds__(256) void lse_rows(
    const float* __restrict__ ll, float* __restrict__ part) {
  int t = threadIdx.x, lane = t & 63, w = t >> 6;
  int b = blockIdx.x * 4 + w;
  const float* row = ll + (size_t)b * Kk;
  float v[8];
  float mx = -3.4e38f;
#pragma unroll
  for (int i = 0; i < 8; i++) { v[i] = row[lane + 64 * i]; mx = fmaxf(mx, v[i]); }
#pragma unroll
  for (int o = 32; o; o >>= 1) mx = fmaxf(mx, __shfl_xor(mx, o, 64));
  float se = 0.f;
#pragma unroll
  for (int i = 0; i < 8; i++) se += expf(v[i] - mx);
#pragma unroll
  for (int o = 32; o; o >>= 1) se += __shfl_xor(se, o, 64);
  __shared__ float r4[4];
  if (lane == 0) r4[w] = -(mx + logf(se));
  __syncthreads();
  if (t == 0) part[blockIdx.x] = r4[0] + r4[1] + r4[2] + r4[3];
}

// ---------------- Kernel E2: final mean ----------------
__global__ __launch_bounds__(256) void final_mean(
    const float* __restrict__ part, float* __restrict__ out) {
  int t = threadIdx.x, lane = t & 63, w = t >> 6;
  float acc = 0.f;
  for (int i = t; i < 2048; i += 256) acc += part[i];
#pragma unroll
  for (int o = 32; o; o >>= 1) acc += __shfl_down(acc, o, 64);
  __shared__ float r4[4];
  if (lane == 0) r4[w] = acc;
  __syncthreads();
  if (t == 0) out[0] = (r4[0] + r4[1] + r4[2] + r4[3]) * (1.0f / 8192.0f);
}

extern "C" void kernel_launch(void* const* d_in, const int* in_sizes, int n_in,
                              void* d_out, int out_size, void* d_ws, size_t ws_size,
                              hipStream_t stream) {
  const float* x         = (const float*)d_in[0];
  const float* mu        = (const float*)d_in[1];
  const float* dir_raw   = (const float*)d_in[2];
  const float* scale_rho = (const float*)d_in[3];
  const float* psi_rho   = (const float*)d_in[4];
  const float* pi_logits = (const float*)d_in[5];
  float* out = (float*)d_out;
  char* ws = (char*)d_ws;

  float* psi_inv          = (float*)(ws + OFF_PSI);
  float* logdetPsi        = (float*)(ws + OFF_LDP);
  float* logpi            = (float*)(ws + OFF_LOGPI);
  float* offk             = (float*)(ws + OFF_OFFK);
  float* Minv             = (float*)(ws + OFF_MINV);
  float* xPx              = (float*)(ws + OFF_XPX);
  unsigned short* xbf     = (unsigned short*)(ws + OFF_XBF);
  unsigned short* Gt      = (unsigned short*)(ws + OFF_GT);
  float* ll               = (float*)(ws + OFF_LL);
  float* part             = (float*)(ws + OFF_PART);

  prep_psi<<<1, 256, 0, stream>>>(psi_rho, pi_logits, psi_inv, logdetPsi, logpi);
  prep_k<<<Kk, 256, 0, stream>>>(mu, dir_raw, scale_rho, psi_inv, logdetPsi, logpi,
                                 offk, Minv, Gt);
  prep_x<<<Bn, 256, 0, stream>>>(x, psi_inv, xbf, xPx);
  dim3 g(Nn / BN, Bn / BM);  // (32, 64)
  gemm_ll<<<g, 256, 0, stream>>>(xbf, Gt, Minv, offk, xPx, ll);
  lse_rows<<<Bn / 4, 256, 0, stream>>>(ll, part);
  final_mean<<<1, 256, 0, stream>>>(part, out);
}